// Round 2
// baseline (642.557 us; speedup 1.0000x reference)
//
#include <hip/hip_runtime.h>

typedef unsigned short u16;
typedef __attribute__((ext_vector_type(8))) short short8;     // 8 bf16 (4 VGPRs)
typedef __attribute__((ext_vector_type(4))) float floatx4;    // 4 fp32 acc

#define B_ 4
#define T_ 2048
#define CH 64

__device__ __forceinline__ u16 f2bf(float f) {
  unsigned int x = __float_as_uint(f);
  return (u16)((x + 0x7FFFu + ((x >> 16) & 1u)) >> 16);
}
__device__ __forceinline__ float bf2f(u16 u) {
  union { unsigned int i; float f; } v; v.i = ((unsigned int)u) << 16; return v.f;
}

// lgkm-only barrier: all cross-wave hazards in chain_kernel are LDS (Sb/rhsT/uT).
// Global operands are read-only precomputed tensors, so we must NOT drain vmcnt
// here -- that is what lets global prefetches survive across phases and chunks.
__device__ __forceinline__ void barrier_lgkm() {
  asm volatile("s_waitcnt lgkmcnt(0)\n\ts_barrier" ::: "memory");
}

// ---------------------------------------------------------------------------
// x fp32 -> bf16 (full tensor). grid (B_*T_), 256 thr x 4 elems.
// ---------------------------------------------------------------------------
__global__ __launch_bounds__(256) void xconv_kernel(const float* __restrict__ x,
                                                    u16* __restrict__ Xbf) {
  size_t idx = ((size_t)blockIdx.x * 256 + threadIdx.x) * 4;
  float4 v = *reinterpret_cast<const float4*>(&x[idx]);
  ushort4 o;
  o.x = f2bf(v.x); o.y = f2bf(v.y); o.z = f2bf(v.z); o.w = f2bf(v.w);
  *reinterpret_cast<ushort4*>(&Xbf[idx]) = o;
}

// ---------------------------------------------------------------------------
// Weight transpose+convert: T[n][k] = bf16(W[k][n]). grid (16,16,4).
// ---------------------------------------------------------------------------
__global__ __launch_bounds__(256) void wtrans_kernel(
    const float* __restrict__ W0, const float* __restrict__ W1,
    const float* __restrict__ W2, const float* __restrict__ W3,
    u16* __restrict__ T0, u16* __restrict__ T1,
    u16* __restrict__ T2, u16* __restrict__ T3)
{
  const int z = blockIdx.z;
  const float* W = (z == 0) ? W0 : (z == 1) ? W1 : (z == 2) ? W2 : W3;
  u16* T = (z == 0) ? T0 : (z == 1) ? T1 : (z == 2) ? T2 : T3;
  const int k0 = blockIdx.x * 64, n0 = blockIdx.y * 64;
  const int tid = threadIdx.x;
  __shared__ float Tile[64][65];
#pragma unroll
  for (int i = 0; i < 4; ++i) {
    int lin = tid + i * 256;
    int r = lin >> 4, c4 = (lin & 15) * 4;
    *reinterpret_cast<float4*>(&Tile[r][c4]) =
        *reinterpret_cast<const float4*>(&W[(size_t)(k0 + r) * 1024 + n0 + c4]);
  }
  __syncthreads();
#pragma unroll
  for (int i = 0; i < 4; ++i) {
    int lin = tid + i * 256;
    int r = lin >> 4, c4 = (lin & 15) * 4;   // r: n-within, c4: k-within
    ushort4 o;
    o.x = f2bf(Tile[c4 + 0][r]); o.y = f2bf(Tile[c4 + 1][r]);
    o.z = f2bf(Tile[c4 + 2][r]); o.w = f2bf(Tile[c4 + 3][r]);
    *reinterpret_cast<ushort4*>(&T[(size_t)(n0 + r) * 1024 + k0 + c4]) = o;
  }
}

// ---------------------------------------------------------------------------
// MFMA GEMM for QKV. 128x128 tile, 4 waves (2x2), 4x4 of 16x16x32, BK=32.
// grid (rows/128, 8, 3).
// ---------------------------------------------------------------------------
__global__ __launch_bounds__(256) void mgemm_qkv(
    const u16* __restrict__ Xbf,
    const u16* __restrict__ WqT, const u16* __restrict__ WkT, const u16* __restrict__ WvT,
    u16* __restrict__ Qbf, u16* __restrict__ Kbf, u16* __restrict__ Vbf,
    int tg, int lsh)
{
  const int z = blockIdx.z;
  const u16* BT = (z == 0) ? WqT : ((z == 1) ? WkT : WvT);
  u16* O = (z == 0) ? Qbf : ((z == 1) ? Kbf : Vbf);
  const float scale = (z == 0) ? 0.03125f : 1.0f;
  const int r0 = blockIdx.x * 128, c0 = blockIdx.y * 128;
  const int tid = threadIdx.x;
  const int lane = tid & 63, wave = tid >> 6;
  const int quad = lane >> 4, l16 = lane & 15;
  const int wr = (wave >> 1) * 64, wc = (wave & 1) * 64;

  __shared__ u16 As[128][40];
  __shared__ u16 Bs[128][40];

  const int ar = tid >> 1, ac = (tid & 1) * 16;
  const int lr = r0 + ar;
  const int agrow = ((lr >> lsh) << 11) + tg + (lr & ((1 << lsh) - 1));
  const u16* aptr = &Xbf[(size_t)agrow * 1024 + ac];
  const u16* bptr = &BT[(size_t)(c0 + ar) * 1024 + ac];

  floatx4 acc[4][4] = {};
  for (int k0 = 0; k0 < 1024; k0 += 32) {
    float4 av0 = *reinterpret_cast<const float4*>(aptr + k0);
    float4 av1 = *reinterpret_cast<const float4*>(aptr + k0 + 8);
    float4 bv0 = *reinterpret_cast<const float4*>(bptr + k0);
    float4 bv1 = *reinterpret_cast<const float4*>(bptr + k0 + 8);
    __syncthreads();
    *reinterpret_cast<float4*>(&As[ar][ac]) = av0;
    *reinterpret_cast<float4*>(&As[ar][ac + 8]) = av1;
    *reinterpret_cast<float4*>(&Bs[ar][ac]) = bv0;
    *reinterpret_cast<float4*>(&Bs[ar][ac + 8]) = bv1;
    __syncthreads();
    short8 afr[4], bfr[4];
#pragma unroll
    for (int i = 0; i < 4; ++i) {
      afr[i] = *reinterpret_cast<const short8*>(&As[wr + i * 16 + l16][quad * 8]);
      bfr[i] = *reinterpret_cast<const short8*>(&Bs[wc + i * 16 + l16][quad * 8]);
    }
#pragma unroll
    for (int mi = 0; mi < 4; ++mi)
#pragma unroll
      for (int ni = 0; ni < 4; ++ni)
        acc[mi][ni] = __builtin_amdgcn_mfma_f32_16x16x32_bf16(afr[mi], bfr[ni], acc[mi][ni], 0, 0, 0);
  }
#pragma unroll
  for (int mi = 0; mi < 4; ++mi)
#pragma unroll
    for (int reg = 0; reg < 4; ++reg) {
      int row = r0 + wr + mi * 16 + quad * 4 + reg;
#pragma unroll
      for (int ni = 0; ni < 4; ++ni) {
        int col = c0 + wc + ni * 16 + l16;
        O[(size_t)row * 1024 + col] = f2bf(acc[mi][ni][reg] * scale);
      }
    }
}

// ---------------------------------------------------------------------------
// MFMA GEMM out-proj: fp32 out. grid (rows/128, 8)
// ---------------------------------------------------------------------------
__global__ __launch_bounds__(256) void mgemm_out(
    const u16* __restrict__ Obf, const u16* __restrict__ WoT,
    float* __restrict__ out, int tg, int lsh)
{
  const int r0 = blockIdx.x * 128, c0 = blockIdx.y * 128;
  const int tid = threadIdx.x;
  const int lane = tid & 63, wave = tid >> 6;
  const int quad = lane >> 4, l16 = lane & 15;
  const int wr = (wave >> 1) * 64, wc = (wave & 1) * 64;

  __shared__ u16 As[128][40];
  __shared__ u16 Bs[128][40];

  const int ar = tid >> 1, ac = (tid & 1) * 16;
  const u16* aptr = &Obf[(size_t)(r0 + ar) * 1024 + ac];
  const u16* bptr = &WoT[(size_t)(c0 + ar) * 1024 + ac];

  floatx4 acc[4][4] = {};
  for (int k0 = 0; k0 < 1024; k0 += 32) {
    float4 av0 = *reinterpret_cast<const float4*>(aptr + k0);
    float4 av1 = *reinterpret_cast<const float4*>(aptr + k0 + 8);
    float4 bv0 = *reinterpret_cast<const float4*>(bptr + k0);
    float4 bv1 = *reinterpret_cast<const float4*>(bptr + k0 + 8);
    __syncthreads();
    *reinterpret_cast<float4*>(&As[ar][ac]) = av0;
    *reinterpret_cast<float4*>(&As[ar][ac + 8]) = av1;
    *reinterpret_cast<float4*>(&Bs[ar][ac]) = bv0;
    *reinterpret_cast<float4*>(&Bs[ar][ac + 8]) = bv1;
    __syncthreads();
    short8 afr[4], bfr[4];
#pragma unroll
    for (int i = 0; i < 4; ++i) {
      afr[i] = *reinterpret_cast<const short8*>(&As[wr + i * 16 + l16][quad * 8]);
      bfr[i] = *reinterpret_cast<const short8*>(&Bs[wc + i * 16 + l16][quad * 8]);
    }
#pragma unroll
    for (int mi = 0; mi < 4; ++mi)
#pragma unroll
      for (int ni = 0; ni < 4; ++ni)
        acc[mi][ni] = __builtin_amdgcn_mfma_f32_16x16x32_bf16(afr[mi], bfr[ni], acc[mi][ni], 0, 0, 0);
  }
#pragma unroll
  for (int mi = 0; mi < 4; ++mi)
#pragma unroll
    for (int reg = 0; reg < 4; ++reg) {
      int lr = r0 + wr + mi * 16 + quad * 4 + reg;
      int grow = ((lr >> lsh) << 11) + tg + (lr & ((1 << lsh) - 1));
#pragma unroll
      for (int ni = 0; ni < 4; ++ni) {
        int col = c0 + wc + ni * 16 + l16;
        out[(size_t)grow * 1024 + col] = acc[mi][ni][reg];
      }
    }
}

// ---------------------------------------------------------------------------
// Row-normalize Kbf in place (bf16, fp32 math). grid (rows).
// ---------------------------------------------------------------------------
__global__ __launch_bounds__(256) void knorm_kernel(u16* __restrict__ Kbf) {
  const int row = blockIdx.x;
  const int tid = threadIdx.x;
  ushort4 v4 = *reinterpret_cast<const ushort4*>(&Kbf[(size_t)row * 1024 + tid * 4]);
  float a = bf2f(v4.x), b = bf2f(v4.y), c = bf2f(v4.z), d = bf2f(v4.w);
  float ss = a * a + b * b + c * c + d * d;
#pragma unroll
  for (int off = 32; off > 0; off >>= 1) ss += __shfl_down(ss, off);
  __shared__ float wsum[4];
  if ((tid & 63) == 0) wsum[tid >> 6] = ss;
  __syncthreads();
  float tot = wsum[0] + wsum[1] + wsum[2] + wsum[3];
  float inv = 1.0f / fmaxf(sqrtf(tot), 1e-12f);
  ushort4 o;
  o.x = f2bf(a * inv); o.y = f2bf(b * inv); o.z = f2bf(c * inv); o.w = f2bf(d * inv);
  *reinterpret_cast<ushort4*>(&Kbf[(size_t)row * 1024 + tid * 4]) = o;
}

// ---------------------------------------------------------------------------
// Transpose Kbf -> KT[b][d][t_local] (bf16). grid (tgs/64, 16, B_), 256 thr.
// ---------------------------------------------------------------------------
__global__ __launch_bounds__(256) void ktrans_kernel(const u16* __restrict__ Kbf,
                                                     u16* __restrict__ KT,
                                                     int tgs) {
  const int t0 = blockIdx.x * 64;
  const int d0 = blockIdx.y * 64;
  const int b = blockIdx.z;
  const int tid = threadIdx.x;
  __shared__ u16 Tile[64][68];
#pragma unroll
  for (int i = 0; i < 4; ++i) {
    int lin = tid + i * 256;
    int r = lin >> 4, c4 = (lin & 15) * 4;
    *reinterpret_cast<ushort4*>(&Tile[r][c4]) =
        *reinterpret_cast<const ushort4*>(&Kbf[(size_t)(b * tgs + t0 + r) * 1024 + d0 + c4]);
  }
  __syncthreads();
#pragma unroll
  for (int i = 0; i < 4; ++i) {
    int lin = tid + i * 256;
    int r = lin >> 4, c4 = (lin & 15) * 4;
    ushort4 o;
    o.x = Tile[c4 + 0][r]; o.y = Tile[c4 + 1][r];
    o.z = Tile[c4 + 2][r]; o.w = Tile[c4 + 3][r];
    *reinterpret_cast<ushort4*>(&KT[((size_t)b * 1024 + d0 + r) * tgs + t0 + c4]) = o;
  }
}

// ---------------------------------------------------------------------------
// Per (chunk, batch): MFMA QK^T/KK^T -> P and A -> W=(I+A)^{-1} -> bf16.
// grid (cpg, B_), 256 threads.
// ---------------------------------------------------------------------------
__global__ __launch_bounds__(256) void attn_winv_kernel(
    const u16* __restrict__ Qbf, const u16* __restrict__ Kbf,
    u16* __restrict__ Pb, u16* __restrict__ Wb, int tgs)
{
  const int cc = blockIdx.x;
  const int b = blockIdx.y;
  const int base = b * tgs + cc * CH;
  const int tid = threadIdx.x;
  const int lane = tid & 63;
  const int wave = tid >> 6;
  const int quad = lane >> 4, l16 = lane & 15;
  const int m0 = wave * 16;

  __shared__ float Asm[64][64];
  __shared__ float Wsm[64][65];

  floatx4 accA[4] = {};
  floatx4 accP[4] = {};
  const u16* arowK = &Kbf[(size_t)(base + m0 + l16) * 1024];
  const u16* arowQ = &Qbf[(size_t)(base + m0 + l16) * 1024];
#pragma unroll 4
  for (int kk = 0; kk < 32; ++kk) {
    short8 aK = *reinterpret_cast<const short8*>(&arowK[kk * 32 + quad * 8]);
    short8 aQ = *reinterpret_cast<const short8*>(&arowQ[kk * 32 + quad * 8]);
#pragma unroll
    for (int nt = 0; nt < 4; ++nt) {
      short8 bK = *reinterpret_cast<const short8*>(
          &Kbf[(size_t)(base + nt * 16 + l16) * 1024 + kk * 32 + quad * 8]);
      accA[nt] = __builtin_amdgcn_mfma_f32_16x16x32_bf16(aK, bK, accA[nt], 0, 0, 0);
      accP[nt] = __builtin_amdgcn_mfma_f32_16x16x32_bf16(aQ, bK, accP[nt], 0, 0, 0);
    }
  }
  const size_t pw0 = ((size_t)(cc * B_ + b) * CH) * 64;
#pragma unroll
  for (int nt = 0; nt < 4; ++nt) {
#pragma unroll
    for (int reg = 0; reg < 4; ++reg) {
      int t = m0 + quad * 4 + reg;
      int i = nt * 16 + l16;
      Asm[t][i] = (i < t) ? accA[nt][reg] : 0.0f;
      Pb[pw0 + (size_t)t * 64 + i] = f2bf((i <= t) ? accP[nt][reg] : 0.0f);
    }
  }
  __syncthreads();

  if (tid < 64) {
    const int j = tid;
    for (int t = 0; t < 64; ++t) {
      float s = (t == j) ? 1.0f : 0.0f;
      for (int i = 0; i < t; ++i) s -= Asm[t][i] * Wsm[i][j];
      Wsm[t][j] = s;
    }
    for (int t = 0; t < 64; ++t)
      Wb[pw0 + (size_t)t * 64 + j] = f2bf(Wsm[t][j]);
  }
}

// ---------------------------------------------------------------------------
// Persistent-state MFMA chain, register-resident fp32 S.
// v2 changes vs previous round (which measured 398 us, MfmaUtil 5.4%):
//  (a) lgkm-only barriers: all in-loop hazards are LDS; global loads survive
//      barriers, enabling cross-phase / cross-chunk prefetch (old __syncthreads
//      emitted s_waitcnt vmcnt(0) and force-drained every prefetch).
//  (b) phase A is a depth-1 software pipeline (load kb+1 A-frags while MFMAing
//      kb); last iteration preloads NEXT chunk's first A-frags across the
//      end-of-chunk barrier.
//  (c) KT frags (16 x b128 = 64 VGPRs) load-interleaved into phase A and pinned
//      live via an asm use, so phase C never stalls on global latency
//      (VGPR_Count was 80 -> compiler had sunk these loads to their use).
//  (d) XCD-clustered wg->(b,slice) map: 2 XCDs per batch so each XCD's L2 only
//      streams one batch's K/Q/KT (FETCH was 237 MB vs ~67 MB unique).
// ---------------------------------------------------------------------------
__global__ __launch_bounds__(512, 2) void chain_kernel(
    const u16* __restrict__ Qbf, const u16* __restrict__ Kbf,
    const u16* __restrict__ KT, const u16* __restrict__ Vbf,
    u16* __restrict__ Obf, const u16* __restrict__ Wb, const u16* __restrict__ Pb,
    float* __restrict__ Sglob, int lsh, int cpg, int g, int ngrp)
{
  const int wg = blockIdx.x;
  // Dispatch round-robins blockIdx across 8 XCDs (xcd = wg & 7). Cluster so
  // XCD pair {2b, 2b+1} hosts exactly batch b's 64 slices. Bijective.
  const int t8 = wg & 7;
  const int b = t8 >> 1;
  const int sl = ((wg >> 3) << 1) | (t8 & 1);
  const int c0 = sl * 16;
  const int tgs = 1 << lsh;
  const int tid = threadIdx.x;
  const int lane = tid & 63;
  const int wave = tid >> 6;
  const int quad = lane >> 4, l16 = lane & 15;
  const int d0w = wave * 128;
  const bool isK = (wave < 4);
  const int m0 = (isK ? wave : (wave - 4)) * 16;

  __shared__ u16 Sb[16][1048];   // bf16 shadow (524 words/row = 12 mod 32)
  __shared__ u16 rhsT[16][88];   // (V - KS)^T bf16 (44 words = 12 mod 32)
  __shared__ u16 uT[16][88];     // u^T bf16

  // fp32 master S in registers: Sreg[nt][reg] <-> S[c=quad*4+reg][d=d0w+nt*16+l16]
  floatx4 Sreg[8];
  if (g == 0) {
#pragma unroll
    for (int nt = 0; nt < 8; ++nt) Sreg[nt] = (floatx4){0.f, 0.f, 0.f, 0.f};
    for (int idx = tid; idx < 16 * 256; idx += 512) {
      int r = idx >> 8, d4 = (idx & 255) * 4;
      ushort4 z4 = {0, 0, 0, 0};
      *reinterpret_cast<ushort4*>(&Sb[r][d4]) = z4;
    }
  } else {
#pragma unroll
    for (int nt = 0; nt < 8; ++nt)
#pragma unroll
      for (int reg = 0; reg < 4; ++reg)
        Sreg[nt][reg] = Sglob[((size_t)b * 1024 + c0 + quad * 4 + reg) * 1024 +
                              d0w + nt * 16 + l16];
    for (int idx = tid; idx < 16 * 1024; idx += 512) {
      int r = idx >> 10, d = idx & 1023;
      Sb[r][d] = f2bf(Sglob[((size_t)b * 1024 + c0 + r) * 1024 + d]);
    }
  }
  __syncthreads();

  // Depth-1 cross-chunk A-frag pipeline: pa* always holds frags for current kb.
  const u16* const Abase = isK ? Kbf : Qbf;
  const u16* arow = Abase + (size_t)(b * tgs + m0 + l16) * 1024;  // chunk 0
  short8 pa0 = *reinterpret_cast<const short8*>(arow + 0 * 32 + quad * 8);
  short8 pa1 = *reinterpret_cast<const short8*>(arow + 1 * 32 + quad * 8);
  short8 pa2 = *reinterpret_cast<const short8*>(arow + 2 * 32 + quad * 8);
  short8 pa3 = *reinterpret_cast<const short8*>(arow + 3 * 32 + quad * 8);

  for (int cc = 0; cc < cpg; ++cc) {
    const int base = b * tgs + cc * CH;
    const size_t pw0 = ((size_t)(cc * B_ + b) * CH) * 64;

    // ---- chunk-top loads (waits deferred; covered by phase A) ----
    float vv[4];
    if (isK) {
#pragma unroll
      for (int reg = 0; reg < 4; ++reg)
        vv[reg] = bf2f(Vbf[(size_t)(base + m0 + quad * 4 + reg) * 1024 + c0 + l16]);
    }
    short8 wpf0, wpf1;   // W row frags (K-waves) or P row frags (Q-waves)
    {
      const u16* row = (isK ? Wb : Pb) + pw0 + (size_t)(m0 + l16) * 64;
      wpf0 = *reinterpret_cast<const short8*>(row + quad * 8);
      wpf1 = *reinterpret_cast<const short8*>(row + 32 + quad * 8);
    }

    // ---- phase A: KS (K-waves) / QS (Q-waves), 4 chains, depth-1 pipeline,
    //      KT frag loads interleaved (2 per iteration) ----
    short8 ktf[8][2];
    floatx4 ac0 = {}, ac1 = {}, ac2 = {}, ac3 = {};
#pragma unroll
    for (int kk8 = 0; kk8 < 8; ++kk8) {
      const int kb = kk8 * 4;
      {
        const u16* ktrow = &KT[((size_t)b * 1024 + d0w + kk8 * 16 + l16) * tgs + cc * CH];
        ktf[kk8][0] = *reinterpret_cast<const short8*>(ktrow + quad * 8);
        ktf[kk8][1] = *reinterpret_cast<const short8*>(ktrow + 32 + quad * 8);
      }
      const u16* nap = (kk8 < 7) ? (arow + (kb + 4) * 32)
                                 : (arow + (cc + 1 < cpg ? CH * 1024 : 0));
      short8 na0 = *reinterpret_cast<const short8*>(nap + 0 * 32 + quad * 8);
      short8 na1 = *reinterpret_cast<const short8*>(nap + 1 * 32 + quad * 8);
      short8 na2 = *reinterpret_cast<const short8*>(nap + 2 * 32 + quad * 8);
      short8 na3 = *reinterpret_cast<const short8*>(nap + 3 * 32 + quad * 8);
      short8 b0 = *reinterpret_cast<const short8*>(&Sb[l16][(kb + 0) * 32 + quad * 8]);
      short8 b1 = *reinterpret_cast<const short8*>(&Sb[l16][(kb + 1) * 32 + quad * 8]);
      short8 b2 = *reinterpret_cast<const short8*>(&Sb[l16][(kb + 2) * 32 + quad * 8]);
      short8 b3 = *reinterpret_cast<const short8*>(&Sb[l16][(kb + 3) * 32 + quad * 8]);
      ac0 = __builtin_amdgcn_mfma_f32_16x16x32_bf16(pa0, b0, ac0, 0, 0, 0);
      ac1 = __builtin_amdgcn_mfma_f32_16x16x32_bf16(pa1, b1, ac1, 0, 0, 0);
      ac2 = __builtin_amdgcn_mfma_f32_16x16x32_bf16(pa2, b2, ac2, 0, 0, 0);
      ac3 = __builtin_amdgcn_mfma_f32_16x16x32_bf16(pa3, b3, ac3, 0, 0, 0);
      pa0 = na0; pa1 = na1; pa2 = na2; pa3 = na3;
    }
    floatx4 accS = (ac0 + ac1) + (ac2 + ac3);

    // Pin KT frags live here: forces the loads to have been ISSUED during
    // phase A (wait lands now, fully covered), instead of being sunk into
    // phase C where their latency would be exposed on the serial path.
    asm volatile("" ::
      "v"(ktf[0][0]), "v"(ktf[0][1]), "v"(ktf[1][0]), "v"(ktf[1][1]),
      "v"(ktf[2][0]), "v"(ktf[2][1]), "v"(ktf[3][0]), "v"(ktf[3][1]),
      "v"(ktf[4][0]), "v"(ktf[4][1]), "v"(ktf[5][0]), "v"(ktf[5][1]),
      "v"(ktf[6][0]), "v"(ktf[6][1]), "v"(ktf[7][0]), "v"(ktf[7][1]));

    // ---- rhs = V - KS (K-waves) ----
    if (isK) {
#pragma unroll
      for (int reg = 0; reg < 4; ++reg)
        rhsT[l16][m0 + quad * 4 + reg] = f2bf(vv[reg] - accS[reg]);
    }
    barrier_lgkm();

    // ---- u = W * rhs (K-waves) ----
    if (isK) {
      floatx4 uacc = {};
      short8 br0 = *reinterpret_cast<const short8*>(&rhsT[l16][quad * 8]);
      short8 br1 = *reinterpret_cast<const short8*>(&rhsT[l16][32 + quad * 8]);
      uacc = __builtin_amdgcn_mfma_f32_16x16x32_bf16(wpf0, br0, uacc, 0, 0, 0);
      uacc = __builtin_amdgcn_mfma_f32_16x16x32_bf16(wpf1, br1, uacc, 0, 0, 0);
#pragma unroll
      for (int reg = 0; reg < 4; ++reg)
        uT[l16][m0 + quad * 4 + reg] = f2bf(uacc[reg]);
    }
    barrier_lgkm();

    // ---- o = QS + P*u (Q-waves) ----
    if (!isK) {
      floatx4 oacc = accS;
      short8 bu0 = *reinterpret_cast<const short8*>(&uT[l16][quad * 8]);
      short8 bu1 = *reinterpret_cast<const short8*>(&uT[l16][32 + quad * 8]);
      oacc = __builtin_amdgcn_mfma_f32_16x16x32_bf16(wpf0, bu0, oacc, 0, 0, 0);
      oacc = __builtin_amdgcn_mfma_f32_16x16x32_bf16(wpf1, bu1, oacc, 0, 0, 0);
#pragma unroll
      for (int reg = 0; reg < 4; ++reg) {
        int t = m0 + quad * 4 + reg;
        Obf[(size_t)(base + t) * 1024 + c0 + l16] = f2bf(oacc[reg]);
      }
    }

    // ---- phase C: Sreg += u^T K (wave covers d0w..d0w+127) ----
    {
      short8 ua0 = *reinterpret_cast<const short8*>(&uT[l16][quad * 8]);
      short8 ua1 = *reinterpret_cast<const short8*>(&uT[l16][32 + quad * 8]);
#pragma unroll
      for (int nt = 0; nt < 8; ++nt) {
        floatx4 cf = Sreg[nt];
        cf = __builtin_amdgcn_mfma_f32_16x16x32_bf16(ua0, ktf[nt][0], cf, 0, 0, 0);
        cf = __builtin_amdgcn_mfma_f32_16x16x32_bf16(ua1, ktf[nt][1], cf, 0, 0, 0);
        Sreg[nt] = cf;
        const int dn = d0w + nt * 16;
#pragma unroll
        for (int reg = 0; reg < 4; ++reg)
          Sb[quad * 4 + reg][dn + l16] = f2bf(cf[reg]);
      }
    }
    barrier_lgkm();
    arow += CH * 1024;
  }

  // spill S for next group (only for small-ws tiers; full tier has ngrp==1)
  if (g < ngrp - 1) {
#pragma unroll
    for (int nt = 0; nt < 8; ++nt)
#pragma unroll
      for (int reg = 0; reg < 4; ++reg)
        Sglob[((size_t)b * 1024 + c0 + quad * 4 + reg) * 1024 + d0w + nt * 16 + l16] =
            Sreg[nt][reg];
  }
}

// ---------------------------------------------------------------------------
extern "C" void kernel_launch(void* const* d_in, const int* in_sizes, int n_in,
                              void* d_out, int out_size, void* d_ws, size_t ws_size,
                              hipStream_t stream) {
  const float* x  = (const float*)d_in[0];
  const float* Wq = (const float*)d_in[1];
  const float* Wk = (const float*)d_in[2];
  const float* Wv = (const float*)d_in[3];
  const float* Wo = (const float*)d_in[4];
  float* out = (float*)d_out;

  // tier: largest time-group that fits ws
  int lsh = 8;
  {
    const int cand[4] = {11, 10, 9, 8};
    for (int i = 0; i < 4; ++i) {
      size_t tgs = (size_t)1 << cand[i];
      size_t C = (size_t)B_ * tgs * 1024;
      size_t cpg = tgs / CH;
      size_t need = (size_t)B_ * T_ * 1024 * 2              // Xbf
                  + 4 * ((size_t)1024 * 1024 * 2)           // WT x4
                  + 5 * (C * 2)                             // Qbf,Kbf,Vbf,KT,Obf
                  + 2 * (cpg * B_ * CH * 64 * 2)            // Pb,Wb
                  + (size_t)B_ * 1024 * 1024 * 4            // Sglob
                  + 32768;
      if (need <= ws_size) { lsh = cand[i]; break; }
    }
  }
  const int tgs = 1 << lsh;
  const int cpg = tgs / CH;
  const int ngrp = T_ / tgs;
  const int rows = B_ * tgs;

  char* ws = (char*)d_ws;
  size_t off = 0;
  auto alloc = [&](size_t bytes) -> void* {
    void* p = ws + off;
    off += (bytes + 255) & ~(size_t)255;
    return p;
  };
  u16* Xbf = (u16*)alloc((size_t)B_ * T_ * 1024 * 2);
  u16* WqT = (u16*)alloc((size_t)1024 * 1024 * 2);
  u16* WkT = (u16*)alloc((size_t)1024 * 1024 * 2);
  u16* WvT = (u16*)alloc((size_t)1024 * 1024 * 2);
  u16* WoT = (u16*)alloc((size_t)1024 * 1024 * 2);
  u16* Qbf = (u16*)alloc((size_t)rows * 1024 * 2);
  u16* Kbf = (u16*)alloc((size_t)rows * 1024 * 2);
  u16* Vbf = (u16*)alloc((size_t)rows * 1024 * 2);
  u16* KT  = (u16*)alloc((size_t)rows * 1024 * 2);
  u16* Obf = (u16*)alloc((size_t)rows * 1024 * 2);
  u16* Pb  = (u16*)alloc((size_t)cpg * B_ * CH * 64 * 2);
  u16* Wb  = (u16*)alloc((size_t)cpg * B_ * CH * 64 * 2);
  float* Sglob = (float*)alloc((size_t)B_ * 1024 * 1024 * 4);

  xconv_kernel<<<B_ * T_, 256, 0, stream>>>(x, Xbf);
  wtrans_kernel<<<dim3(16, 16, 4), 256, 0, stream>>>(Wq, Wk, Wv, Wo, WqT, WkT, WvT, WoT);

  for (int g = 0; g < ngrp; ++g) {
    int tg = g * tgs;
    mgemm_qkv<<<dim3(rows / 128, 8, 3), 256, 0, stream>>>(Xbf, WqT, WkT, WvT,
                                                          Qbf, Kbf, Vbf, tg, lsh);
    knorm_kernel<<<rows, 256, 0, stream>>>(Kbf);
    ktrans_kernel<<<dim3(tgs / 64, 16, B_), 256, 0, stream>>>(Kbf, KT, tgs);
    attn_winv_kernel<<<dim3(cpg, B_), 256, 0, stream>>>(Qbf, Kbf, Pb, Wb, tgs);
    chain_kernel<<<256, 512, 0, stream>>>(Qbf, Kbf, KT, Vbf, Obf, Wb, Pb, Sglob,
                                          lsh, cpg, g, ngrp);
    mgemm_out<<<dim3(rows / 128, 8), 256, 0, stream>>>(Obf, WoT, out, tg, lsh);
  }
}

// Round 4
// 628.108 us; speedup vs baseline: 1.0230x; 1.0230x over previous
//
#include <hip/hip_runtime.h>

typedef unsigned short u16;
typedef __attribute__((ext_vector_type(8))) short short8;     // 8 bf16 (4 VGPRs)
typedef __attribute__((ext_vector_type(4))) float floatx4;    // 4 fp32 acc

#define B_ 4
#define T_ 2048
#define CH 64

__device__ __forceinline__ u16 f2bf(float f) {
  unsigned int x = __float_as_uint(f);
  return (u16)((x + 0x7FFFu + ((x >> 16) & 1u)) >> 16);
}
__device__ __forceinline__ float bf2f(u16 u) {
  union { unsigned int i; float f; } v; v.i = ((unsigned int)u) << 16; return v.f;
}

// lgkm-only barrier: all cross-wave hazards in chain_kernel are LDS (Sb/rhsT/uT).
__device__ __forceinline__ void barrier_lgkm() {
  asm volatile("s_waitcnt lgkmcnt(0)\n\ts_barrier" ::: "memory");
}

// Opaque asm loads: the compiler cannot sink, duplicate, or rematerialize these,
// so prefetch issue points and vmcnt counts are fully under our control.
#define GL(dst, addr, IMM) \
  asm volatile("global_load_dwordx4 %0, %1, off offset:" #IMM : "=v"(dst) : "v"(addr))
#define GLU(dst, addr, IMM) \
  asm volatile("global_load_ushort %0, %1, off offset:" #IMM : "=v"(dst) : "v"(addr))
#define GS(addr, val, IMM) \
  asm volatile("global_store_short %0, %1, off offset:" #IMM :: "v"(addr), "v"(val))

#define GLA(slot, base, I0, I1, I2, I3) do { \
  GL(af[slot][0], base, I0); GL(af[slot][1], base, I1); \
  GL(af[slot][2], base, I2); GL(af[slot][3], base, I3); } while (0)

#define GLKT(nt0) do { \
  const u16* kp0_ = ktb + (size_t)(nt0) * ktstep; \
  GL(ktf[nt0][0], kp0_, 0); GL(ktf[nt0][1], kp0_, 64); \
  const u16* kp1_ = ktb + (size_t)(nt0 + 1) * ktstep; \
  GL(ktf[nt0 + 1][0], kp1_, 0); GL(ktf[nt0 + 1][1], kp1_, 64); } while (0)

#define GLX4 do { \
  GL(wpf0, wrow, 0); GL(wpf1, wrow, 64); \
  GLU(vv0, vvb, 0); GLU(vv1, vvb, 2048); \
  GLU(vv2, vvb2, 0); GLU(vv3, vvb2, 2048); } while (0)

#define NOOP ((void)0)

// One phase-A iteration: counted wait (vmcnt never 0), prefetch issues, extra
// (ktf/wpf/vv) issues, then LDS B-frags + 4 MFMAs. sched_barrier keeps MFMAs
// below the wait (rule: MFMA hoists past inline-asm waitcnt otherwise); mask
// 0x387 = ALU|VALU|SALU|DS|DS_READ|DS_WRITE may still flow for scheduling.
#define AITER(K, NW, PREFETCH, XCODE) do { \
  asm volatile("s_waitcnt vmcnt(" #NW ")"); \
  __builtin_amdgcn_sched_barrier(0x387); \
  PREFETCH; \
  XCODE; \
  short8 b0_ = *reinterpret_cast<const short8*>(&Sb[l16][(K * 4 + 0) * 32 + quad * 8]); \
  short8 b1_ = *reinterpret_cast<const short8*>(&Sb[l16][(K * 4 + 1) * 32 + quad * 8]); \
  short8 b2_ = *reinterpret_cast<const short8*>(&Sb[l16][(K * 4 + 2) * 32 + quad * 8]); \
  short8 b3_ = *reinterpret_cast<const short8*>(&Sb[l16][(K * 4 + 3) * 32 + quad * 8]); \
  ac0 = __builtin_amdgcn_mfma_f32_16x16x32_bf16(af[K][0], b0_, ac0, 0, 0, 0); \
  ac1 = __builtin_amdgcn_mfma_f32_16x16x32_bf16(af[K][1], b1_, ac1, 0, 0, 0); \
  ac2 = __builtin_amdgcn_mfma_f32_16x16x32_bf16(af[K][2], b2_, ac2, 0, 0, 0); \
  ac3 = __builtin_amdgcn_mfma_f32_16x16x32_bf16(af[K][3], b3_, ac3, 0, 0, 0); \
} while (0)

// ---------------------------------------------------------------------------
// x fp32 -> bf16 (full tensor). grid (B_*T_), 256 thr x 4 elems.
// ---------------------------------------------------------------------------
__global__ __launch_bounds__(256) void xconv_kernel(const float* __restrict__ x,
                                                    u16* __restrict__ Xbf) {
  size_t idx = ((size_t)blockIdx.x * 256 + threadIdx.x) * 4;
  float4 v = *reinterpret_cast<const float4*>(&x[idx]);
  ushort4 o;
  o.x = f2bf(v.x); o.y = f2bf(v.y); o.z = f2bf(v.z); o.w = f2bf(v.w);
  *reinterpret_cast<ushort4*>(&Xbf[idx]) = o;
}

// ---------------------------------------------------------------------------
// Weight transpose+convert: T[n][k] = bf16(W[k][n]). grid (16,16,4).
// ---------------------------------------------------------------------------
__global__ __launch_bounds__(256) void wtrans_kernel(
    const float* __restrict__ W0, const float* __restrict__ W1,
    const float* __restrict__ W2, const float* __restrict__ W3,
    u16* __restrict__ T0, u16* __restrict__ T1,
    u16* __restrict__ T2, u16* __restrict__ T3)
{
  const int z = blockIdx.z;
  const float* W = (z == 0) ? W0 : (z == 1) ? W1 : (z == 2) ? W2 : W3;
  u16* T = (z == 0) ? T0 : (z == 1) ? T1 : (z == 2) ? T2 : T3;
  const int k0 = blockIdx.x * 64, n0 = blockIdx.y * 64;
  const int tid = threadIdx.x;
  __shared__ float Tile[64][65];
#pragma unroll
  for (int i = 0; i < 4; ++i) {
    int lin = tid + i * 256;
    int r = lin >> 4, c4 = (lin & 15) * 4;
    *reinterpret_cast<float4*>(&Tile[r][c4]) =
        *reinterpret_cast<const float4*>(&W[(size_t)(k0 + r) * 1024 + n0 + c4]);
  }
  __syncthreads();
#pragma unroll
  for (int i = 0; i < 4; ++i) {
    int lin = tid + i * 256;
    int r = lin >> 4, c4 = (lin & 15) * 4;   // r: n-within, c4: k-within
    ushort4 o;
    o.x = f2bf(Tile[c4 + 0][r]); o.y = f2bf(Tile[c4 + 1][r]);
    o.z = f2bf(Tile[c4 + 2][r]); o.w = f2bf(Tile[c4 + 3][r]);
    *reinterpret_cast<ushort4*>(&T[(size_t)(n0 + r) * 1024 + k0 + c4]) = o;
  }
}

// ---------------------------------------------------------------------------
// MFMA GEMM for QKV. 128x128 tile, 4 waves (2x2), 4x4 of 16x16x32, BK=32.
// grid (rows/128, 8, 3).
// ---------------------------------------------------------------------------
__global__ __launch_bounds__(256) void mgemm_qkv(
    const u16* __restrict__ Xbf,
    const u16* __restrict__ WqT, const u16* __restrict__ WkT, const u16* __restrict__ WvT,
    u16* __restrict__ Qbf, u16* __restrict__ Kbf, u16* __restrict__ Vbf,
    int tg, int lsh)
{
  const int z = blockIdx.z;
  const u16* BT = (z == 0) ? WqT : ((z == 1) ? WkT : WvT);
  u16* O = (z == 0) ? Qbf : ((z == 1) ? Kbf : Vbf);
  const float scale = (z == 0) ? 0.03125f : 1.0f;
  const int r0 = blockIdx.x * 128, c0 = blockIdx.y * 128;
  const int tid = threadIdx.x;
  const int lane = tid & 63, wave = tid >> 6;
  const int quad = lane >> 4, l16 = lane & 15;
  const int wr = (wave >> 1) * 64, wc = (wave & 1) * 64;

  __shared__ u16 As[128][40];
  __shared__ u16 Bs[128][40];

  const int ar = tid >> 1, ac = (tid & 1) * 16;
  const int lr = r0 + ar;
  const int agrow = ((lr >> lsh) << 11) + tg + (lr & ((1 << lsh) - 1));
  const u16* aptr = &Xbf[(size_t)agrow * 1024 + ac];
  const u16* bptr = &BT[(size_t)(c0 + ar) * 1024 + ac];

  floatx4 acc[4][4] = {};
  for (int k0 = 0; k0 < 1024; k0 += 32) {
    float4 av0 = *reinterpret_cast<const float4*>(aptr + k0);
    float4 av1 = *reinterpret_cast<const float4*>(aptr + k0 + 8);
    float4 bv0 = *reinterpret_cast<const float4*>(bptr + k0);
    float4 bv1 = *reinterpret_cast<const float4*>(bptr + k0 + 8);
    __syncthreads();
    *reinterpret_cast<float4*>(&As[ar][ac]) = av0;
    *reinterpret_cast<float4*>(&As[ar][ac + 8]) = av1;
    *reinterpret_cast<float4*>(&Bs[ar][ac]) = bv0;
    *reinterpret_cast<float4*>(&Bs[ar][ac + 8]) = bv1;
    __syncthreads();
    short8 afr[4], bfr[4];
#pragma unroll
    for (int i = 0; i < 4; ++i) {
      afr[i] = *reinterpret_cast<const short8*>(&As[wr + i * 16 + l16][quad * 8]);
      bfr[i] = *reinterpret_cast<const short8*>(&Bs[wc + i * 16 + l16][quad * 8]);
    }
#pragma unroll
    for (int mi = 0; mi < 4; ++mi)
#pragma unroll
      for (int ni = 0; ni < 4; ++ni)
        acc[mi][ni] = __builtin_amdgcn_mfma_f32_16x16x32_bf16(afr[mi], bfr[ni], acc[mi][ni], 0, 0, 0);
  }
#pragma unroll
  for (int mi = 0; mi < 4; ++mi)
#pragma unroll
    for (int reg = 0; reg < 4; ++reg) {
      int row = r0 + wr + mi * 16 + quad * 4 + reg;
#pragma unroll
      for (int ni = 0; ni < 4; ++ni) {
        int col = c0 + wc + ni * 16 + l16;
        O[(size_t)row * 1024 + col] = f2bf(acc[mi][ni][reg] * scale);
      }
    }
}

// ---------------------------------------------------------------------------
// MFMA GEMM out-proj: fp32 out. grid (rows/128, 8)
// ---------------------------------------------------------------------------
__global__ __launch_bounds__(256) void mgemm_out(
    const u16* __restrict__ Obf, const u16* __restrict__ WoT,
    float* __restrict__ out, int tg, int lsh)
{
  const int r0 = blockIdx.x * 128, c0 = blockIdx.y * 128;
  const int tid = threadIdx.x;
  const int lane = tid & 63, wave = tid >> 6;
  const int quad = lane >> 4, l16 = lane & 15;
  const int wr = (wave >> 1) * 64, wc = (wave & 1) * 64;

  __shared__ u16 As[128][40];
  __shared__ u16 Bs[128][40];

  const int ar = tid >> 1, ac = (tid & 1) * 16;
  const u16* aptr = &Obf[(size_t)(r0 + ar) * 1024 + ac];
  const u16* bptr = &WoT[(size_t)(c0 + ar) * 1024 + ac];

  floatx4 acc[4][4] = {};
  for (int k0 = 0; k0 < 1024; k0 += 32) {
    float4 av0 = *reinterpret_cast<const float4*>(aptr + k0);
    float4 av1 = *reinterpret_cast<const float4*>(aptr + k0 + 8);
    float4 bv0 = *reinterpret_cast<const float4*>(bptr + k0);
    float4 bv1 = *reinterpret_cast<const float4*>(bptr + k0 + 8);
    __syncthreads();
    *reinterpret_cast<float4*>(&As[ar][ac]) = av0;
    *reinterpret_cast<float4*>(&As[ar][ac + 8]) = av1;
    *reinterpret_cast<float4*>(&Bs[ar][ac]) = bv0;
    *reinterpret_cast<float4*>(&Bs[ar][ac + 8]) = bv1;
    __syncthreads();
    short8 afr[4], bfr[4];
#pragma unroll
    for (int i = 0; i < 4; ++i) {
      afr[i] = *reinterpret_cast<const short8*>(&As[wr + i * 16 + l16][quad * 8]);
      bfr[i] = *reinterpret_cast<const short8*>(&Bs[wc + i * 16 + l16][quad * 8]);
    }
#pragma unroll
    for (int mi = 0; mi < 4; ++mi)
#pragma unroll
      for (int ni = 0; ni < 4; ++ni)
        acc[mi][ni] = __builtin_amdgcn_mfma_f32_16x16x32_bf16(afr[mi], bfr[ni], acc[mi][ni], 0, 0, 0);
  }
#pragma unroll
  for (int mi = 0; mi < 4; ++mi)
#pragma unroll
    for (int reg = 0; reg < 4; ++reg) {
      int lr = r0 + wr + mi * 16 + quad * 4 + reg;
      int grow = ((lr >> lsh) << 11) + tg + (lr & ((1 << lsh) - 1));
#pragma unroll
      for (int ni = 0; ni < 4; ++ni) {
        int col = c0 + wc + ni * 16 + l16;
        out[(size_t)grow * 1024 + col] = acc[mi][ni][reg];
      }
    }
}

// ---------------------------------------------------------------------------
// Row-normalize Kbf in place (bf16, fp32 math). grid (rows).
// ---------------------------------------------------------------------------
__global__ __launch_bounds__(256) void knorm_kernel(u16* __restrict__ Kbf) {
  const int row = blockIdx.x;
  const int tid = threadIdx.x;
  ushort4 v4 = *reinterpret_cast<const ushort4*>(&Kbf[(size_t)row * 1024 + tid * 4]);
  float a = bf2f(v4.x), b = bf2f(v4.y), c = bf2f(v4.z), d = bf2f(v4.w);
  float ss = a * a + b * b + c * c + d * d;
#pragma unroll
  for (int off = 32; off > 0; off >>= 1) ss += __shfl_down(ss, off);
  __shared__ float wsum[4];
  if ((tid & 63) == 0) wsum[tid >> 6] = ss;
  __syncthreads();
  float tot = wsum[0] + wsum[1] + wsum[2] + wsum[3];
  float inv = 1.0f / fmaxf(sqrtf(tot), 1e-12f);
  ushort4 o;
  o.x = f2bf(a * inv); o.y = f2bf(b * inv); o.z = f2bf(c * inv); o.w = f2bf(d * inv);
  *reinterpret_cast<ushort4*>(&Kbf[(size_t)row * 1024 + tid * 4]) = o;
}

// ---------------------------------------------------------------------------
// Transpose Kbf -> KT[b][d][t_local] (bf16). grid (tgs/64, 16, B_), 256 thr.
// ---------------------------------------------------------------------------
__global__ __launch_bounds__(256) void ktrans_kernel(const u16* __restrict__ Kbf,
                                                     u16* __restrict__ KT,
                                                     int tgs) {
  const int t0 = blockIdx.x * 64;
  const int d0 = blockIdx.y * 64;
  const int b = blockIdx.z;
  const int tid = threadIdx.x;
  __shared__ u16 Tile[64][68];
#pragma unroll
  for (int i = 0; i < 4; ++i) {
    int lin = tid + i * 256;
    int r = lin >> 4, c4 = (lin & 15) * 4;
    *reinterpret_cast<ushort4*>(&Tile[r][c4]) =
        *reinterpret_cast<const ushort4*>(&Kbf[(size_t)(b * tgs + t0 + r) * 1024 + d0 + c4]);
  }
  __syncthreads();
#pragma unroll
  for (int i = 0; i < 4; ++i) {
    int lin = tid + i * 256;
    int r = lin >> 4, c4 = (lin & 15) * 4;
    ushort4 o;
    o.x = Tile[c4 + 0][r]; o.y = Tile[c4 + 1][r];
    o.z = Tile[c4 + 2][r]; o.w = Tile[c4 + 3][r];
    *reinterpret_cast<ushort4*>(&KT[((size_t)b * 1024 + d0 + r) * tgs + t0 + c4]) = o;
  }
}

// ---------------------------------------------------------------------------
// Per (chunk, batch): MFMA QK^T/KK^T -> P and A -> W=(I+A)^{-1} -> bf16.
// grid (cpg, B_), 256 threads.
// ---------------------------------------------------------------------------
__global__ __launch_bounds__(256) void attn_winv_kernel(
    const u16* __restrict__ Qbf, const u16* __restrict__ Kbf,
    u16* __restrict__ Pb, u16* __restrict__ Wb, int tgs)
{
  const int cc = blockIdx.x;
  const int b = blockIdx.y;
  const int base = b * tgs + cc * CH;
  const int tid = threadIdx.x;
  const int lane = tid & 63;
  const int wave = tid >> 6;
  const int quad = lane >> 4, l16 = lane & 15;
  const int m0 = wave * 16;

  __shared__ float Asm[64][64];
  __shared__ float Wsm[64][65];

  floatx4 accA[4] = {};
  floatx4 accP[4] = {};
  const u16* arowK = &Kbf[(size_t)(base + m0 + l16) * 1024];
  const u16* arowQ = &Qbf[(size_t)(base + m0 + l16) * 1024];
#pragma unroll 4
  for (int kk = 0; kk < 32; ++kk) {
    short8 aK = *reinterpret_cast<const short8*>(&arowK[kk * 32 + quad * 8]);
    short8 aQ = *reinterpret_cast<const short8*>(&arowQ[kk * 32 + quad * 8]);
#pragma unroll
    for (int nt = 0; nt < 4; ++nt) {
      short8 bK = *reinterpret_cast<const short8*>(
          &Kbf[(size_t)(base + nt * 16 + l16) * 1024 + kk * 32 + quad * 8]);
      accA[nt] = __builtin_amdgcn_mfma_f32_16x16x32_bf16(aK, bK, accA[nt], 0, 0, 0);
      accP[nt] = __builtin_amdgcn_mfma_f32_16x16x32_bf16(aQ, bK, accP[nt], 0, 0, 0);
    }
  }
  const size_t pw0 = ((size_t)(cc * B_ + b) * CH) * 64;
#pragma unroll
  for (int nt = 0; nt < 4; ++nt) {
#pragma unroll
    for (int reg = 0; reg < 4; ++reg) {
      int t = m0 + quad * 4 + reg;
      int i = nt * 16 + l16;
      Asm[t][i] = (i < t) ? accA[nt][reg] : 0.0f;
      Pb[pw0 + (size_t)t * 64 + i] = f2bf((i <= t) ? accP[nt][reg] : 0.0f);
    }
  }
  __syncthreads();

  if (tid < 64) {
    const int j = tid;
    for (int t = 0; t < 64; ++t) {
      float s = (t == j) ? 1.0f : 0.0f;
      for (int i = 0; i < t; ++i) s -= Asm[t][i] * Wsm[i][j];
      Wsm[t][j] = s;
    }
    for (int t = 0; t < 64; ++t)
      Wb[pw0 + (size_t)t * 64 + j] = f2bf(Wsm[t][j]);
  }
}

// ---------------------------------------------------------------------------
// Persistent-state MFMA chain, register-resident fp32 S.
// v3: all in-loop global accesses are opaque inline-asm with hand-counted
// vmcnt waits (never 0 in the loop). Diagnosis from v2: compiler sank /
// duplicated plain-load prefetches (VGPR=96 proved ktf was not held), so each
// of ~90 global ops per chunk paid a serialized ~330cy L2 round trip
// (30k cy/chunk vs ~2k of work; MfmaUtil 5.4%). Volatile asm loads cannot be
// sunk or rematerialized; counted waits keep 10-26 loads in flight.
// Issue order per chunk (vmcnt counts depend on it -- do not reorder):
//   it0..it7: wait(N_k); A-frags(k+2) x4; extras; 4 MFMA
//     extras: it0-3 -> ktf pairs; it4 -> wpf(2)+vv(4); it6/it7 -> next-chunk
//     A-frags into slots 0/1 (8-slot ring, no copies).
//   rhs: wait(12) [covers vv/wpf/ktf]; phases rhs/u/o/C; o-stores last.
// ---------------------------------------------------------------------------
__global__ __launch_bounds__(512, 2) void chain_kernel(
    const u16* __restrict__ Qbf, const u16* __restrict__ Kbf,
    const u16* __restrict__ KT, const u16* __restrict__ Vbf,
    u16* __restrict__ Obf, const u16* __restrict__ Wb, const u16* __restrict__ Pb,
    float* __restrict__ Sglob, int lsh, int cpg, int g, int ngrp)
{
  const int wg = blockIdx.x;
  // XCD pair {2b, 2b+1} hosts exactly batch b's 64 slices (bijective).
  const int t8 = wg & 7;
  const int b = t8 >> 1;
  const int sl = ((wg >> 3) << 1) | (t8 & 1);
  const int c0 = sl * 16;
  const int tgs = 1 << lsh;
  const int tid = threadIdx.x;
  const int lane = tid & 63;
  const int wave = tid >> 6;
  const int quad = lane >> 4, l16 = lane & 15;
  const int d0w = wave * 128;
  const bool isK = (wave < 4);
  const int m0 = (isK ? wave : (wave - 4)) * 16;
  const size_t ktstep = (size_t)16 * tgs;

  __shared__ u16 Sb[16][1048];   // bf16 shadow (524 words/row = 12 mod 32)
  __shared__ u16 rhsT[16][88];   // (V - KS)^T bf16
  __shared__ u16 uT[16][88];     // u^T bf16

  // fp32 master S in registers: Sreg[nt][reg] <-> S[c=quad*4+reg][d=d0w+nt*16+l16]
  floatx4 Sreg[8];
  if (g == 0) {
#pragma unroll
    for (int nt = 0; nt < 8; ++nt) Sreg[nt] = (floatx4){0.f, 0.f, 0.f, 0.f};
    for (int idx = tid; idx < 16 * 256; idx += 512) {
      int r = idx >> 8, d4 = (idx & 255) * 4;
      ushort4 z4 = {0, 0, 0, 0};
      *reinterpret_cast<ushort4*>(&Sb[r][d4]) = z4;
    }
  } else {
#pragma unroll
    for (int nt = 0; nt < 8; ++nt)
#pragma unroll
      for (int reg = 0; reg < 4; ++reg)
        Sreg[nt][reg] = Sglob[((size_t)b * 1024 + c0 + quad * 4 + reg) * 1024 +
                              d0w + nt * 16 + l16];
    for (int idx = tid; idx < 16 * 1024; idx += 512) {
      int r = idx >> 10, d = idx & 1023;
      Sb[r][d] = f2bf(Sglob[((size_t)b * 1024 + c0 + r) * 1024 + d]);
    }
  }
  __syncthreads();   // full drain: vmcnt is 0 entering the loop (counts rely on it)

  const u16* const Abase = isK ? Kbf : Qbf;
  const u16* arow = Abase + (size_t)(b * tgs + m0 + l16) * 1024;  // chunk 0

  short8 af[8][4];    // A-frag ring; slot k holds iter-k frags (literal idx only)
  short8 ktf[8][2];
  short8 wpf0, wpf1;
  unsigned int vv0, vv1, vv2, vv3;

  // Prologue: chunk 0, iter 0/1 A-frags.
  {
    const u16* aq0 = arow + quad * 8;
    GLA(0, aq0, 0, 64, 128, 192);
    GLA(1, aq0, 256, 320, 384, 448);
  }

  for (int cc = 0; cc < cpg; ++cc) {
    const int base = b * tgs + cc * CH;
    const size_t pw0 = ((size_t)(cc * B_ + b) * CH) * 64;

    const u16* aq   = arow + quad * 8;
    const u16* aqn  = arow + (size_t)(cc + 1 < cpg ? CH * 1024 : 0) + quad * 8;
    const u16* ktb  = KT + ((size_t)b * 1024 + d0w + l16) * tgs + (size_t)cc * CH + quad * 8;
    const u16* wrow = (isK ? Wb : Pb) + pw0 + (size_t)(m0 + l16) * 64 + quad * 8;
    const u16* vvb  = Vbf + (size_t)(base + m0 + quad * 4) * 1024 + c0 + l16;
    const u16* vvb2 = vvb + 2048;

    floatx4 ac0 = {}, ac1 = {}, ac2 = {}, ac3 = {};

    AITER(0, 4,  GLA(2, aq, 512, 576, 640, 704),     GLKT(0));
    AITER(1, 8,  GLA(3, aq, 768, 832, 896, 960),     GLKT(2));
    AITER(2, 12, GLA(4, aq, 1024, 1088, 1152, 1216), GLKT(4));
    AITER(3, 12, GLA(5, aq, 1280, 1344, 1408, 1472), GLKT(6));
    AITER(4, 12, GLA(6, aq, 1536, 1600, 1664, 1728), GLX4);
    AITER(5, 14, GLA(7, aq, 1792, 1856, 1920, 1984), NOOP);
    AITER(6, 10, GLA(0, aqn, 0, 64, 128, 192),       NOOP);
    AITER(7, 4,  GLA(1, aqn, 256, 320, 384, 448),    NOOP);

    // Guarantees vv/wpf (X4) done; ktf (X0-X3, older) implied done.
    asm volatile("s_waitcnt vmcnt(12)");
    __builtin_amdgcn_sched_barrier(0);

    floatx4 accS = (ac0 + ac1) + (ac2 + ac3);

    // ---- rhs = V - KS (K-waves) ----
    if (isK) {
      rhsT[l16][m0 + quad * 4 + 0] = f2bf(bf2f((u16)vv0) - accS[0]);
      rhsT[l16][m0 + quad * 4 + 1] = f2bf(bf2f((u16)vv1) - accS[1]);
      rhsT[l16][m0 + quad * 4 + 2] = f2bf(bf2f((u16)vv2) - accS[2]);
      rhsT[l16][m0 + quad * 4 + 3] = f2bf(bf2f((u16)vv3) - accS[3]);
    }
    barrier_lgkm();

    // ---- u = W * rhs (K-waves) ----
    if (isK) {
      floatx4 uacc = {};
      short8 br0 = *reinterpret_cast<const short8*>(&rhsT[l16][quad * 8]);
      short8 br1 = *reinterpret_cast<const short8*>(&rhsT[l16][32 + quad * 8]);
      uacc = __builtin_amdgcn_mfma_f32_16x16x32_bf16(wpf0, br0, uacc, 0, 0, 0);
      uacc = __builtin_amdgcn_mfma_f32_16x16x32_bf16(wpf1, br1, uacc, 0, 0, 0);
#pragma unroll
      for (int reg = 0; reg < 4; ++reg)
        uT[l16][m0 + quad * 4 + reg] = f2bf(uacc[reg]);
    }
    barrier_lgkm();

    // ---- o = QS + P*u (Q-waves), stores via asm (issued after all loads) ----
    if (!isK) {
      floatx4 oacc = accS;
      short8 bu0 = *reinterpret_cast<const short8*>(&uT[l16][quad * 8]);
      short8 bu1 = *reinterpret_cast<const short8*>(&uT[l16][32 + quad * 8]);
      oacc = __builtin_amdgcn_mfma_f32_16x16x32_bf16(wpf0, bu0, oacc, 0, 0, 0);
      oacc = __builtin_amdgcn_mfma_f32_16x16x32_bf16(wpf1, bu1, oacc, 0, 0, 0);
      u16* ob  = Obf + (size_t)(base + m0 + quad * 4) * 1024 + c0 + l16;
      u16* ob2 = ob + 2048;
      unsigned int s0 = f2bf(oacc[0]), s1 = f2bf(oacc[1]);
      unsigned int s2 = f2bf(oacc[2]), s3 = f2bf(oacc[3]);
      GS(ob, s0, 0);  GS(ob, s1, 2048);
      GS(ob2, s2, 0); GS(ob2, s3, 2048);
    }

    // ---- phase C: Sreg += u^T K (wave covers d0w..d0w+127) ----
    {
      short8 ua0 = *reinterpret_cast<const short8*>(&uT[l16][quad * 8]);
      short8 ua1 = *reinterpret_cast<const short8*>(&uT[l16][32 + quad * 8]);
#pragma unroll
      for (int nt = 0; nt < 8; ++nt) {
        floatx4 cf = Sreg[nt];
        cf = __builtin_amdgcn_mfma_f32_16x16x32_bf16(ua0, ktf[nt][0], cf, 0, 0, 0);
        cf = __builtin_amdgcn_mfma_f32_16x16x32_bf16(ua1, ktf[nt][1], cf, 0, 0, 0);
        Sreg[nt] = cf;
        const int dn = d0w + nt * 16;
#pragma unroll
        for (int reg = 0; reg < 4; ++reg)
          Sb[quad * 4 + reg][dn + l16] = f2bf(cf[reg]);
      }
    }
    barrier_lgkm();
    arow += CH * 1024;
  }

  // spill S for next group (only for small-ws tiers; full tier has ngrp==1)
  if (g < ngrp - 1) {
#pragma unroll
    for (int nt = 0; nt < 8; ++nt)
#pragma unroll
      for (int reg = 0; reg < 4; ++reg)
        Sglob[((size_t)b * 1024 + c0 + quad * 4 + reg) * 1024 + d0w + nt * 16 + l16] =
            Sreg[nt][reg];
  }
}

// ---------------------------------------------------------------------------
extern "C" void kernel_launch(void* const* d_in, const int* in_sizes, int n_in,
                              void* d_out, int out_size, void* d_ws, size_t ws_size,
                              hipStream_t stream) {
  const float* x  = (const float*)d_in[0];
  const float* Wq = (const float*)d_in[1];
  const float* Wk = (const float*)d_in[2];
  const float* Wv = (const float*)d_in[3];
  const float* Wo = (const float*)d_in[4];
  float* out = (float*)d_out;

  // tier: largest time-group that fits ws
  int lsh = 8;
  {
    const int cand[4] = {11, 10, 9, 8};
    for (int i = 0; i < 4; ++i) {
      size_t tgs = (size_t)1 << cand[i];
      size_t C = (size_t)B_ * tgs * 1024;
      size_t cpg = tgs / CH;
      size_t need = (size_t)B_ * T_ * 1024 * 2              // Xbf
                  + 4 * ((size_t)1024 * 1024 * 2)           // WT x4
                  + 5 * (C * 2)                             // Qbf,Kbf,Vbf,KT,Obf
                  + 2 * (cpg * B_ * CH * 64 * 2)            // Pb,Wb
                  + (size_t)B_ * 1024 * 1024 * 4            // Sglob
                  + 32768;
      if (need <= ws_size) { lsh = cand[i]; break; }
    }
  }
  const int tgs = 1 << lsh;
  const int cpg = tgs / CH;
  const int ngrp = T_ / tgs;
  const int rows = B_ * tgs;

  char* ws = (char*)d_ws;
  size_t off = 0;
  auto alloc = [&](size_t bytes) -> void* {
    void* p = ws + off;
    off += (bytes + 255) & ~(size_t)255;
    return p;
  };
  u16* Xbf = (u16*)alloc((size_t)B_ * T_ * 1024 * 2);
  u16* WqT = (u16*)alloc((size_t)1024 * 1024 * 2);
  u16* WkT = (u16*)alloc((size_t)1024 * 1024 * 2);
  u16* WvT = (u16*)alloc((size_t)1024 * 1024 * 2);
  u16* WoT = (u16*)alloc((size_t)1024 * 1024 * 2);
  u16* Qbf = (u16*)alloc((size_t)rows * 1024 * 2);
  u16* Kbf = (u16*)alloc((size_t)rows * 1024 * 2);
  u16* Vbf = (u16*)alloc((size_t)rows * 1024 * 2);
  u16* KT  = (u16*)alloc((size_t)rows * 1024 * 2);
  u16* Obf = (u16*)alloc((size_t)rows * 1024 * 2);
  u16* Pb  = (u16*)alloc((size_t)cpg * B_ * CH * 64 * 2);
  u16* Wb  = (u16*)alloc((size_t)cpg * B_ * CH * 64 * 2);
  float* Sglob = (float*)alloc((size_t)B_ * 1024 * 1024 * 4);

  xconv_kernel<<<B_ * T_, 256, 0, stream>>>(x, Xbf);
  wtrans_kernel<<<dim3(16, 16, 4), 256, 0, stream>>>(Wq, Wk, Wv, Wo, WqT, WkT, WvT, WoT);

  for (int g = 0; g < ngrp; ++g) {
    int tg = g * tgs;
    mgemm_qkv<<<dim3(rows / 128, 8, 3), 256, 0, stream>>>(Xbf, WqT, WkT, WvT,
                                                          Qbf, Kbf, Vbf, tg, lsh);
    knorm_kernel<<<rows, 256, 0, stream>>>(Kbf);
    ktrans_kernel<<<dim3(tgs / 64, 16, B_), 256, 0, stream>>>(Kbf, KT, tgs);
    attn_winv_kernel<<<dim3(cpg, B_), 256, 0, stream>>>(Qbf, Kbf, Pb, Wb, tgs);
    chain_kernel<<<256, 512, 0, stream>>>(Qbf, Kbf, KT, Vbf, Obf, Wb, Pb, Sglob,
                                          lsh, cpg, g, ngrp);
    mgemm_out<<<dim3(rows / 128, 8), 256, 0, stream>>>(Obf, WoT, out, tg, lsh);
  }
}